// Round 23
// baseline (44.023 us; speedup 1.0000x reference)
//
#include <hip/hip_runtime.h>
#include <math.h>

#define N_PTS 16384
#define M_TGT 16384
#define TPN 8192
#define DUB2 4.0f
#define BMASK_WORDS (4*64*64*64/32)
#define SCAT_NB 16

__device__ __forceinline__ unsigned int mono_key(float f) {
    unsigned int u = __float_as_uint(f);
    return (u & 0x80000000u) ? ~u : (u | 0x80000000u);
}

// 33 integer offsets with dx^2+dy^2+dz^2 <= 4, grouped by d2 = 0,1,2,3,4.
__device__ const signed char NOFF[33][3] = {
    {0,0,0},
    {1,0,0},{-1,0,0},{0,1,0},{0,-1,0},{0,0,1},{0,0,-1},
    {1,1,0},{1,-1,0},{-1,1,0},{-1,-1,0},{1,0,1},{1,0,-1},{-1,0,1},{-1,0,-1},
    {0,1,1},{0,1,-1},{0,-1,1},{0,-1,-1},
    {1,1,1},{1,1,-1},{1,-1,1},{1,-1,-1},{-1,1,1},{-1,1,-1},{-1,-1,1},{-1,-1,-1},
    {2,0,0},{-2,0,0},{0,2,0},{0,-2,0},{0,0,2},{0,0,-2}
};

// K1: round-11 proven gemm (16 rows/block). Zeroes bmask.
// (Three register-blocking attempts — r13/r16/r22 — all regressed; keep this.)
__global__ __launch_bounds__(256) void k_gemm(const float* __restrict__ fea,
        const float* __restrict__ Wup, const float* __restrict__ Wcls,
        float* __restrict__ out_pred, float* __restrict__ out_fea,
        unsigned int* __restrict__ bmask) {
    __shared__ float Ws[64 * 64];
    __shared__ float fs[16 * 68];
    const int tid = threadIdx.x;
    const int r0 = blockIdx.x * 16;

    if (tid < 32) bmask[blockIdx.x * 32 + tid] = 0u;

    for (int t = tid; t < 1024; t += 256)
        ((float4*)Ws)[t] = ((const float4*)Wup)[t];
    {
        float4 v = ((const float4*)(fea + r0 * 64))[tid];
        int r = tid >> 4, c = (tid & 15) * 4;
        fs[r*68 + c + 0] = v.x; fs[r*68 + c + 1] = v.y;
        fs[r*68 + c + 2] = v.z; fs[r*68 + c + 3] = v.w;
    }
    __syncthreads();

    const int cg = tid & 15;
    const int r  = tid >> 4;
    float a0 = 0.f, a1 = 0.f, a2 = 0.f, a3 = 0.f;
    const float* fr = fs + r * 68;
    #pragma unroll
    for (int k = 0; k < 64; ++k) {
        float f = fr[k];
        float4 w = *(const float4*)&Ws[k * 64 + cg * 4];
        a0 = fmaf(f, w.x, a0); a1 = fmaf(f, w.y, a1);
        a2 = fmaf(f, w.z, a2); a3 = fmaf(f, w.w, a3);
    }
    a0 = fmaxf(a0, 0.f); a1 = fmaxf(a1, 0.f);
    a2 = fmaxf(a2, 0.f); a3 = fmaxf(a3, 0.f);
    const int row = r0 + r;
    *(float4*)&out_fea[row * 64 + cg * 4] = make_float4(a0, a1, a2, a3);

    float4 wc = *(const float4*)&Wcls[cg * 4];
    float s = a0*wc.x + a1*wc.y + a2*wc.z + a3*wc.w;
    for (int off = 1; off < 16; off <<= 1) s += __shfl_xor(s, off, 16);
    if (cg == 0) out_pred[row] = s;
}

// K2 (round-20 proven, 16 blocks x 1024): bitmask build + per-block
// pass-0 partial histogram (plain stores, no init dependency).
__global__ __launch_bounds__(1024) void k_scat(const float* __restrict__ pred,
        const int* __restrict__ tc, unsigned int* __restrict__ bmask,
        unsigned int* __restrict__ phist) {
    __shared__ unsigned int whist[16][256];
    const int tid = threadIdx.x;
    const int blk = blockIdx.x;
    const int id = blk * 1024 + tid;

    for (int t = tid; t < 16 * 256; t += 1024) ((unsigned int*)whist)[t] = 0u;

    int4 c = *(const int4*)&tc[id * 4];
    int key = ((c.x * 64 + c.y) * 64 + c.z) * 64 + c.w;
    atomicOr(&bmask[key >> 5], 1u << (key & 31));

    __syncthreads();
    unsigned int u = mono_key(pred[id]);
    atomicAdd(&whist[tid >> 6][u >> 24], 1u);
    __syncthreads();
    if (tid < 256) {
        unsigned int s = 0u;
        #pragma unroll
        for (int w = 0; w < 16; ++w) s += whist[w][tid];
        phist[blk * 256 + tid] = s;
    }
}

// K3 (round-20 proven): redundant per-block select (1024 thr, float4 loads,
// 16-way whist) + probe + epilogue. 64 rows/block.
// IDEMPOTENT (kscale in {0,1}, outputs rewritten identically) — launched
// TWICE this round to measure its duration: delta vs 31.04 = F + 1 boundary.
__global__ __launch_bounds__(1024) void k_final(const int* __restrict__ coords,
        const unsigned int* __restrict__ bmask, const unsigned int* __restrict__ phist,
        const float* __restrict__ out_pred, float* __restrict__ out_fea,
        float* __restrict__ out_keep, float* __restrict__ out_kt,
        float* __restrict__ out_loss) {
    __shared__ unsigned int whist[16][256];     // 16 KB
    __shared__ unsigned int lhist[256];
    __shared__ unsigned int scanb[256];
    __shared__ unsigned int sh_prefix, sh_rank;
    __shared__ float kscale[64];
    const int tid = threadIdx.x;
    const int w = tid >> 6;
    const int r0 = blockIdx.x * 64;

    // ---- select (redundant per block) ----
    if (tid < 256) {
        unsigned int s = 0u;
        #pragma unroll
        for (int b = 0; b < SCAT_NB; ++b) s += phist[b * 256 + tid];
        lhist[tid] = s;
    }
    if (tid == 0) { sh_prefix = 0u; sh_rank = TPN - 1; }
    __syncthreads();

    for (int pass = 0; pass < 4; ++pass) {
        const int shift = 24 - pass * 8;
        const unsigned int prefix = sh_prefix;
        const unsigned int rank = sh_rank;
        if (pass > 0) {
            for (int t = tid; t < 16 * 256; t += 1024) ((unsigned int*)whist)[t] = 0u;
            __syncthreads();
            for (int i = tid; i < N_PTS / 4; i += 1024) {
                float4 v = ((const float4*)out_pred)[i];
                unsigned int u0 = mono_key(v.x), u1 = mono_key(v.y);
                unsigned int u2 = mono_key(v.z), u3 = mono_key(v.w);
                if ((u0 >> (shift + 8)) == prefix) atomicAdd(&whist[w][(u0 >> shift) & 255u], 1u);
                if ((u1 >> (shift + 8)) == prefix) atomicAdd(&whist[w][(u1 >> shift) & 255u], 1u);
                if ((u2 >> (shift + 8)) == prefix) atomicAdd(&whist[w][(u2 >> shift) & 255u], 1u);
                if ((u3 >> (shift + 8)) == prefix) atomicAdd(&whist[w][(u3 >> shift) & 255u], 1u);
            }
            __syncthreads();
            if (tid < 256) {
                unsigned int s = 0u;
                #pragma unroll
                for (int ww = 0; ww < 16; ++ww) s += whist[ww][tid];
                lhist[tid] = s;
            }
            __syncthreads();
        }
        if (tid < 64) {                      // single-wave inclusive scan (256 bins)
            uint4 h = ((const uint4*)lhist)[tid];
            unsigned int s0 = h.x, s1 = s0 + h.y, s2 = s1 + h.z, s3 = s2 + h.w;
            unsigned int tot = s3;
            for (int d = 1; d < 64; d <<= 1) {
                unsigned int v = __shfl_up(tot, d);
                if (tid >= d) tot += v;
            }
            unsigned int base = tot - s3;
            scanb[tid*4 + 0] = base + s0;
            scanb[tid*4 + 1] = base + s1;
            scanb[tid*4 + 2] = base + s2;
            scanb[tid*4 + 3] = base + s3;
        }
        __syncthreads();
        if (tid < 256) {
            unsigned int hi = scanb[tid];
            unsigned int lo = hi - lhist[tid];
            if (rank >= lo && rank < hi) {
                sh_prefix = (prefix << 8) | (unsigned int)tid;
                sh_rank = rank - lo;
            }
        }
        __syncthreads();
    }
    const unsigned int uth = sh_prefix;
    const float thres = (uth & 0x80000000u) ? __uint_as_float(uth ^ 0x80000000u)
                                            : __uint_as_float(~uth);

    // ---- probe + epilogue ----
    if (tid < 64) {
        const int i = r0 + tid;
        float p = out_pred[i];
        int4 c = *(const int4*)&coords[i * 4];
        const int b = c.x, x = c.y, y = c.z, z = c.w;
        int key0 = ((b * 64 + x) * 64 + y) * 64 + z;
        bool kt = (bmask[key0 >> 5] >> (key0 & 31)) & 1u;
        float dists;
        if (kt) {
            dists = 0.f;
        } else {
            dists = 5.f;                     // sentinel > DUB2: "not found"
            int t = 1;
            #pragma unroll
            for (int g = 1; g <= 4; ++g) {
                const int gend = (g == 1) ? 7 : (g == 2) ? 19 : (g == 3) ? 27 : 33;
                bool hit = false;
                for (; t < gend; ++t) {
                    int ox = x + NOFF[t][0], oy = y + NOFF[t][1], oz = z + NOFF[t][2];
                    if (((unsigned)ox | (unsigned)oy | (unsigned)oz) < 64u) {
                        int key = ((b * 64 + ox) * 64 + oy) * 64 + oz;
                        hit |= (bmask[key >> 5] >> (key & 31)) & 1u;
                    }
                }
                if (hit) { dists = (float)g; break; }
            }
        }
        bool keep0 = (p <= thres);
        bool pm = (p > DUB2), tm = (dists > DUB2);
        float loss = (pm && tm) ? p : ((!pm && tm) ? DUB2 : dists);
        bool kf = keep0 || kt;
        out_keep[i] = kf ? 1.f : 0.f;
        out_kt[i]  = kt ? 1.f : 0.f;
        out_loss[i] = loss;
        kscale[tid] = kf ? 1.f : 0.f;
    }
    __syncthreads();
    {
        float4* fbase = (float4*)(out_fea + r0 * 64);
        int v = tid;                          // 64 rows x 16 float4 = 1024
        float sc = kscale[v >> 4];
        float4 xv = fbase[v];
        xv.x *= sc; xv.y *= sc; xv.z *= sc; xv.w *= sc;
        fbase[v] = xv;
    }
}

extern "C" void kernel_launch(void* const* d_in, const int* in_sizes, int n_in,
                              void* d_out, int out_size, void* d_ws, size_t ws_size,
                              hipStream_t stream) {
    const float* fea     = (const float*)d_in[0];
    const float* Wup     = (const float*)d_in[1];
    const float* Wcls    = (const float*)d_in[2];
    const int*   coords  = (const int*)d_in[3];
    const int*   tcoords = (const int*)d_in[4];

    float* out      = (float*)d_out;
    float* out_pred = out;
    float* out_fea  = out + N_PTS;
    float* out_keep = out + N_PTS + N_PTS * 64;
    float* out_kt   = out_keep + N_PTS;
    float* out_loss = out_kt + N_PTS;

    char* ws = (char*)d_ws;
    unsigned int* bmask = (unsigned int*)(ws + 64);            // 128 KB -> 131136
    unsigned int* phist = (unsigned int*)(ws + 131136);        // 16 KB  (16 x 256 u32)

    k_gemm <<<N_PTS / 16, 256, 0, stream>>>(fea, Wup, Wcls, out_pred, out_fea, bmask);
    k_scat <<<SCAT_NB, 1024, 0, stream>>>(out_pred, tcoords, bmask, phist);
    // MEASUREMENT: k_final launched twice (idempotent) — delta vs 31.04 us
    // = one k_final duration + one dispatch boundary.
    k_final<<<N_PTS / 64, 1024, 0, stream>>>(coords, bmask, phist,
                                             out_pred, out_fea, out_keep, out_kt, out_loss);
    k_final<<<N_PTS / 64, 1024, 0, stream>>>(coords, bmask, phist,
                                             out_pred, out_fea, out_keep, out_kt, out_loss);
}

// Round 25
// 36.026 us; speedup vs baseline: 1.2220x; 1.2220x over previous
//
#include <hip/hip_runtime.h>
#include <math.h>

#define N_PTS 16384
#define M_TGT 16384
#define TPN 8192
#define DUB2 4.0f
#define BMASK_WORDS (4*64*64*64/32)

__device__ __forceinline__ unsigned int mono_key(float f) {
    unsigned int u = __float_as_uint(f);
    return (u & 0x80000000u) ? ~u : (u | 0x80000000u);
}

// 33 integer offsets with dx^2+dy^2+dz^2 <= 4; 4th component = d2 group.
__device__ const signed char NOFF4[33][4] = {
    {0,0,0,0},
    {1,0,0,1},{-1,0,0,1},{0,1,0,1},{0,-1,0,1},{0,0,1,1},{0,0,-1,1},
    {1,1,0,2},{1,-1,0,2},{-1,1,0,2},{-1,-1,0,2},{1,0,1,2},{1,0,-1,2},{-1,0,1,2},{-1,0,-1,2},
    {0,1,1,2},{0,1,-1,2},{0,-1,1,2},{0,-1,-1,2},
    {1,1,1,3},{1,1,-1,3},{1,-1,1,3},{1,-1,-1,3},{-1,1,1,3},{-1,1,-1,3},{-1,-1,1,3},{-1,-1,-1,3},
    {2,0,0,4},{-2,0,0,4},{0,2,0,4},{0,-2,0,4},{0,0,2,4},{0,0,-2,4}
};

// wave-0 scan-locate over a 256-bin LDS histogram: find bin containing rank r,
// write bin -> *sh_b, remaining rank -> *sh_r. Caller barriers around it.
__device__ __forceinline__ void scan_locate256(const unsigned int* h256,
        unsigned int r, unsigned int* sh_b, unsigned int* sh_r, int tid) {
    const int lane = tid & 63;
    if ((tid >> 6) == 0) {
        uint4 h = ((const uint4*)h256)[lane];
        unsigned int ss = h.x + h.y + h.z + h.w;
        unsigned int inc = ss;
        for (int d = 1; d < 64; d <<= 1) {
            unsigned int t = __shfl_up(inc, d);
            if (lane >= d) inc += t;
        }
        unsigned int exc = inc - ss;
        bool has = (r >= exc && r < exc + ss);
        unsigned long long m = __ballot(has);
        if (m != 0ull && lane == __ffsll(m) - 1) {
            unsigned int rr = r - exc;
            if (rr < h.x)                   { *sh_b = lane*4u;    *sh_r = rr; }
            else if (rr < h.x+h.y)          { *sh_b = lane*4u+1u; *sh_r = rr-h.x; }
            else if (rr < h.x+h.y+h.z)      { *sh_b = lane*4u+2u; *sh_r = rr-h.x-h.y; }
            else                            { *sh_b = lane*4u+3u; *sh_r = rr-h.x-h.y-h.z; }
        }
    }
}

// K1: round-11 proven gemm (16 rows/block). Zeroes bmask + hist16.
__global__ __launch_bounds__(256) void k_gemm(const float* __restrict__ fea,
        const float* __restrict__ Wup, const float* __restrict__ Wcls,
        float* __restrict__ out_pred, float* __restrict__ out_fea,
        unsigned int* __restrict__ bmask, unsigned int* __restrict__ hist16) {
    __shared__ float Ws[64 * 64];
    __shared__ float fs[16 * 68];
    const int tid = threadIdx.x;
    const int r0 = blockIdx.x * 16;

    if (tid < 32) bmask[blockIdx.x * 32 + tid] = 0u;            // 1024*32 = 32768
    else if (tid < 96) hist16[blockIdx.x * 64 + tid - 32] = 0u; // 1024*64 = 65536

    for (int t = tid; t < 1024; t += 256)
        ((float4*)Ws)[t] = ((const float4*)Wup)[t];
    {
        float4 v = ((const float4*)(fea + r0 * 64))[tid];
        int r = tid >> 4, c = (tid & 15) * 4;
        fs[r*68 + c + 0] = v.x; fs[r*68 + c + 1] = v.y;
        fs[r*68 + c + 2] = v.z; fs[r*68 + c + 3] = v.w;
    }
    __syncthreads();

    const int cg = tid & 15;
    const int r  = tid >> 4;
    float a0 = 0.f, a1 = 0.f, a2 = 0.f, a3 = 0.f;
    const float* fr = fs + r * 68;
    #pragma unroll
    for (int k = 0; k < 64; ++k) {
        float f = fr[k];
        float4 w = *(const float4*)&Ws[k * 64 + cg * 4];
        a0 = fmaf(f, w.x, a0); a1 = fmaf(f, w.y, a1);
        a2 = fmaf(f, w.z, a2); a3 = fmaf(f, w.w, a3);
    }
    a0 = fmaxf(a0, 0.f); a1 = fmaxf(a1, 0.f);
    a2 = fmaxf(a2, 0.f); a3 = fmaxf(a3, 0.f);
    const int row = r0 + r;
    *(float4*)&out_fea[row * 64 + cg * 4] = make_float4(a0, a1, a2, a3);

    float4 wc = *(const float4*)&Wcls[cg * 4];
    float s = a0*wc.x + a1*wc.y + a2*wc.z + a3*wc.w;
    for (int off = 1; off < 16; off <<= 1) s += __shfl_xor(s, off, 16);
    if (cg == 0) out_pred[row] = s;
}

// K2: 64 blocks x 256 — bitmask build + global 65536-bin histogram of the
// top 16 bits of mono_key(pred). No LDS, no barriers.
__global__ __launch_bounds__(256) void k_scat(const float* __restrict__ pred,
        const int* __restrict__ tc, unsigned int* __restrict__ bmask,
        unsigned int* __restrict__ hist16) {
    const int id = blockIdx.x * 256 + threadIdx.x;
    int4 c = *(const int4*)&tc[id * 4];
    int key = ((c.x * 64 + c.y) * 64 + c.z) * 64 + c.w;
    atomicOr(&bmask[key >> 5], 1u << (key & 31));
    unsigned int u = mono_key(pred[id]);
    atomicAdd(&hist16[u >> 16], 1u);
}

// K3: per-block threshold from hist16 (block scan + one filtered pred scan +
// tiny LDS-list radix; exact fallback if list overflows) + parallel probe
// (16 thr/row x 2 offsets, shfl-min) + epilogue. 64 rows/block.
__global__ __launch_bounds__(1024) void k_final(const int* __restrict__ coords,
        const unsigned int* __restrict__ bmask, const unsigned int* __restrict__ hist16,
        const float* __restrict__ out_pred, float* __restrict__ out_fea,
        float* __restrict__ out_keep, float* __restrict__ out_kt,
        float* __restrict__ out_loss) {
    __shared__ unsigned int wtot[16];
    __shared__ unsigned int sh_bin16, sh_rank2, sh_cnt;
    __shared__ unsigned int list[1024];
    __shared__ unsigned int h256[256];
    __shared__ unsigned int sh_b, sh_r;
    __shared__ float kscale[64];
    const int tid = threadIdx.x;
    const int lane = tid & 63;
    const int w = tid >> 6;
    const int r0 = blockIdx.x * 64;
    const unsigned int rank = TPN - 1;

    // ---- locate bin16 (top 16 bits) via block scan of hist16 ----
    const uint4* h16v = (const uint4*)hist16;
    unsigned int s = 0;
    #pragma unroll
    for (int i = 0; i < 16; ++i) {
        uint4 h = h16v[tid * 16 + i];
        s += h.x + h.y + h.z + h.w;
    }
    unsigned int incl = s;
    for (int d = 1; d < 64; d <<= 1) {
        unsigned int t = __shfl_up(incl, d);
        if (lane >= d) incl += t;
    }
    if (lane == 63) wtot[w] = incl;
    if (tid == 0) sh_cnt = 0u;
    __syncthreads();
    if (w == 0) {
        unsigned int x = (lane < 16) ? wtot[lane] : 0u;
        for (int d = 1; d < 16; d <<= 1) {
            unsigned int t = __shfl_up(x, d);
            if (lane >= d) x += t;
        }
        if (lane < 16) wtot[lane] = x;
    }
    __syncthreads();
    unsigned int excl = ((w == 0) ? 0u : wtot[w - 1]) + incl - s;
    if (rank >= excl && rank < excl + s) {
        unsigned int r = rank - excl;
        unsigned int bin = 0, rin = 0; bool found = false;
        for (int i = 0; i < 16 && !found; ++i) {
            uint4 h = h16v[tid * 16 + i];
            unsigned int base = tid * 64 + i * 4;
            if (r < h.x)                  { bin = base;     rin = r; found = true; }
            else if (r < h.x+h.y)         { bin = base + 1; rin = r - h.x; found = true; }
            else if (r < h.x+h.y+h.z)     { bin = base + 2; rin = r - h.x - h.y; found = true; }
            else if (r < h.x+h.y+h.z+h.w) { bin = base + 3; rin = r - h.x - h.y - h.z; found = true; }
            else r -= h.x + h.y + h.z + h.w;
        }
        sh_bin16 = bin; sh_rank2 = rin;
    }
    __syncthreads();
    const unsigned int bin16 = sh_bin16;
    const unsigned int rank2 = sh_rank2;

    // ---- collect keys matching bin16 (store low 16 bits) ----
    for (int i = tid; i < N_PTS / 4; i += 1024) {
        float4 v = ((const float4*)out_pred)[i];
        unsigned int u0 = mono_key(v.x), u1 = mono_key(v.y);
        unsigned int u2 = mono_key(v.z), u3 = mono_key(v.w);
        if ((u0 >> 16) == bin16) { unsigned int p = atomicAdd(&sh_cnt, 1u); if (p < 1024u) list[p] = u0 & 0xFFFFu; }
        if ((u1 >> 16) == bin16) { unsigned int p = atomicAdd(&sh_cnt, 1u); if (p < 1024u) list[p] = u1 & 0xFFFFu; }
        if ((u2 >> 16) == bin16) { unsigned int p = atomicAdd(&sh_cnt, 1u); if (p < 1024u) list[p] = u2 & 0xFFFFu; }
        if ((u3 >> 16) == bin16) { unsigned int p = atomicAdd(&sh_cnt, 1u); if (p < 1024u) list[p] = u3 & 0xFFFFu; }
    }
    __syncthreads();
    const unsigned int cnt = sh_cnt;
    unsigned int b2, b3;

    if (cnt <= 1024u) {                       // list path (order-independent rank)
        if (tid < 256) h256[tid] = 0u;
        __syncthreads();
        if (tid < (int)cnt) atomicAdd(&h256[list[tid] >> 8], 1u);
        __syncthreads();
        scan_locate256(h256, rank2, &sh_b, &sh_r, tid);
        __syncthreads();
        b2 = sh_b;
        unsigned int rank3 = sh_r;
        if (tid < 256) h256[tid] = 0u;
        __syncthreads();
        if (tid < (int)cnt) { unsigned int e = list[tid]; if ((e >> 8) == b2) atomicAdd(&h256[e & 255u], 1u); }
        __syncthreads();
        scan_locate256(h256, rank3, &sh_b, &sh_r, tid);
        __syncthreads();
        b3 = sh_b;
    } else {                                  // exact fallback: filtered pred scans
        if (tid < 256) h256[tid] = 0u;
        __syncthreads();
        for (int i = tid; i < N_PTS / 4; i += 1024) {
            float4 v = ((const float4*)out_pred)[i];
            unsigned int u0 = mono_key(v.x), u1 = mono_key(v.y);
            unsigned int u2 = mono_key(v.z), u3 = mono_key(v.w);
            if ((u0 >> 16) == bin16) atomicAdd(&h256[(u0 >> 8) & 255u], 1u);
            if ((u1 >> 16) == bin16) atomicAdd(&h256[(u1 >> 8) & 255u], 1u);
            if ((u2 >> 16) == bin16) atomicAdd(&h256[(u2 >> 8) & 255u], 1u);
            if ((u3 >> 16) == bin16) atomicAdd(&h256[(u3 >> 8) & 255u], 1u);
        }
        __syncthreads();
        scan_locate256(h256, rank2, &sh_b, &sh_r, tid);
        __syncthreads();
        b2 = sh_b;
        unsigned int rank3 = sh_r;
        unsigned int pfx24 = (bin16 << 8) | b2;
        if (tid < 256) h256[tid] = 0u;
        __syncthreads();
        for (int i = tid; i < N_PTS / 4; i += 1024) {
            float4 v = ((const float4*)out_pred)[i];
            unsigned int u0 = mono_key(v.x), u1 = mono_key(v.y);
            unsigned int u2 = mono_key(v.z), u3 = mono_key(v.w);
            if ((u0 >> 8) == pfx24) atomicAdd(&h256[u0 & 255u], 1u);
            if ((u1 >> 8) == pfx24) atomicAdd(&h256[u1 & 255u], 1u);
            if ((u2 >> 8) == pfx24) atomicAdd(&h256[u2 & 255u], 1u);
            if ((u3 >> 8) == pfx24) atomicAdd(&h256[u3 & 255u], 1u);
        }
        __syncthreads();
        scan_locate256(h256, rank3, &sh_b, &sh_r, tid);
        __syncthreads();
        b3 = sh_b;
    }
    const unsigned int uth = (bin16 << 16) | (b2 << 8) | b3;
    const float thres = (uth & 0x80000000u) ? __uint_as_float(uth ^ 0x80000000u)
                                            : __uint_as_float(~uth);

    // ---- parallel probe: 16 threads/row, 2 offsets each + shfl-min ----
    {
        const int row = tid >> 4;
        const int sub = tid & 15;
        const int i = r0 + row;
        float p = out_pred[i];
        int4 c = *(const int4*)&coords[i * 4];
        const int b = c.x, x = c.y, y = c.z, z = c.w;
        int key0 = ((b * 64 + x) * 64 + y) * 64 + z;
        bool kt = (bmask[key0 >> 5] >> (key0 & 31)) & 1u;
        float dists;
        if (kt) {
            dists = 0.f;
        } else {
            float best = 5.f;                 // sentinel > DUB2: "not found"
            #pragma unroll
            for (int q = 0; q < 2; ++q) {
                int t = 1 + sub + q * 16;     // t in [1,33)
                int ox = x + NOFF4[t][0], oy = y + NOFF4[t][1], oz = z + NOFF4[t][2];
                if (((unsigned)ox | (unsigned)oy | (unsigned)oz) < 64u) {
                    int key = ((b * 64 + ox) * 64 + oy) * 64 + oz;
                    if ((bmask[key >> 5] >> (key & 31)) & 1u)
                        best = fminf(best, (float)NOFF4[t][3]);
                }
            }
            for (int d = 1; d < 16; d <<= 1)
                best = fminf(best, __shfl_xor(best, d, 16));
            dists = best;
        }
        if (sub == 0) {
            bool keep0 = (p <= thres);
            bool pm = (p > DUB2), tm = (dists > DUB2);
            float loss = (pm && tm) ? p : ((!pm && tm) ? DUB2 : dists);
            bool kf = keep0 || kt;
            out_keep[i] = kf ? 1.f : 0.f;
            out_kt[i]  = kt ? 1.f : 0.f;
            out_loss[i] = loss;
            kscale[row] = kf ? 1.f : 0.f;
        }
    }
    __syncthreads();
    {
        float4* fbase = (float4*)(out_fea + r0 * 64);
        int v = tid;                          // 64 rows x 16 float4 = 1024
        float sc = kscale[v >> 4];
        float4 xv = fbase[v];
        xv.x *= sc; xv.y *= sc; xv.z *= sc; xv.w *= sc;
        fbase[v] = xv;
    }
}

extern "C" void kernel_launch(void* const* d_in, const int* in_sizes, int n_in,
                              void* d_out, int out_size, void* d_ws, size_t ws_size,
                              hipStream_t stream) {
    const float* fea     = (const float*)d_in[0];
    const float* Wup     = (const float*)d_in[1];
    const float* Wcls    = (const float*)d_in[2];
    const int*   coords  = (const int*)d_in[3];
    const int*   tcoords = (const int*)d_in[4];

    float* out      = (float*)d_out;
    float* out_pred = out;
    float* out_fea  = out + N_PTS;
    float* out_keep = out + N_PTS + N_PTS * 64;
    float* out_kt   = out_keep + N_PTS;
    float* out_loss = out_kt + N_PTS;

    char* ws = (char*)d_ws;
    unsigned int* bmask  = (unsigned int*)(ws + 64);       // 128 KB -> 131136
    unsigned int* hist16 = (unsigned int*)(ws + 131136);   // 256 KB -> 393280

    k_gemm <<<N_PTS / 16, 256, 0, stream>>>(fea, Wup, Wcls, out_pred, out_fea,
                                            bmask, hist16);
    k_scat <<<64, 256, 0, stream>>>(out_pred, tcoords, bmask, hist16);
    k_final<<<N_PTS / 64, 1024, 0, stream>>>(coords, bmask, hist16,
                                             out_pred, out_fea, out_keep, out_kt, out_loss);
}

// Round 26
// 28.666 us; speedup vs baseline: 1.5357x; 1.2568x over previous
//
#include <hip/hip_runtime.h>
#include <math.h>

#define N_PTS 16384
#define M_TGT 16384
#define TPN 8192
#define DUB2 4.0f
#define BMASK_WORDS (4*64*64*64/32)
#define SCAT_NB 16

__device__ __forceinline__ unsigned int mono_key(float f) {
    unsigned int u = __float_as_uint(f);
    return (u & 0x80000000u) ? ~u : (u | 0x80000000u);
}

// 33 integer offsets with dx^2+dy^2+dz^2 <= 4; 4th component = d2 group.
__device__ const signed char NOFF4[33][4] = {
    {0,0,0,0},
    {1,0,0,1},{-1,0,0,1},{0,1,0,1},{0,-1,0,1},{0,0,1,1},{0,0,-1,1},
    {1,1,0,2},{1,-1,0,2},{-1,1,0,2},{-1,-1,0,2},{1,0,1,2},{1,0,-1,2},{-1,0,1,2},{-1,0,-1,2},
    {0,1,1,2},{0,1,-1,2},{0,-1,1,2},{0,-1,-1,2},
    {1,1,1,3},{1,1,-1,3},{1,-1,1,3},{1,-1,-1,3},{-1,1,1,3},{-1,1,-1,3},{-1,-1,1,3},{-1,-1,-1,3},
    {2,0,0,4},{-2,0,0,4},{0,2,0,4},{0,-2,0,4},{0,0,2,4},{0,0,-2,4}
};

// wave-0 scan-locate over a 256-bin LDS histogram: find bin containing rank r,
// write bin -> *sh_b, remaining rank -> *sh_r. Caller barriers around it.
__device__ __forceinline__ void scan_locate256(const unsigned int* h256,
        unsigned int r, unsigned int* sh_b, unsigned int* sh_r, int tid) {
    const int lane = tid & 63;
    if ((tid >> 6) == 0) {
        uint4 h = ((const uint4*)h256)[lane];
        unsigned int ss = h.x + h.y + h.z + h.w;
        unsigned int inc = ss;
        for (int d = 1; d < 64; d <<= 1) {
            unsigned int t = __shfl_up(inc, d);
            if (lane >= d) inc += t;
        }
        unsigned int exc = inc - ss;
        bool has = (r >= exc && r < exc + ss);
        unsigned long long m = __ballot(has);
        if (m != 0ull && lane == __ffsll(m) - 1) {
            unsigned int rr = r - exc;
            if (rr < h.x)                   { *sh_b = lane*4u;    *sh_r = rr; }
            else if (rr < h.x+h.y)          { *sh_b = lane*4u+1u; *sh_r = rr-h.x; }
            else if (rr < h.x+h.y+h.z)      { *sh_b = lane*4u+2u; *sh_r = rr-h.x-h.y; }
            else                            { *sh_b = lane*4u+3u; *sh_r = rr-h.x-h.y-h.z; }
        }
    }
}

// K1: round-11 proven gemm (16 rows/block). Zeroes bmask + hist16.
__global__ __launch_bounds__(256) void k_gemm(const float* __restrict__ fea,
        const float* __restrict__ Wup, const float* __restrict__ Wcls,
        float* __restrict__ out_pred, float* __restrict__ out_fea,
        unsigned int* __restrict__ bmask, unsigned int* __restrict__ hist16) {
    __shared__ float Ws[64 * 64];
    __shared__ float fs[16 * 68];
    const int tid = threadIdx.x;
    const int r0 = blockIdx.x * 16;

    if (tid < 32) bmask[blockIdx.x * 32 + tid] = 0u;            // 1024*32 = 32768
    else if (tid < 96) hist16[blockIdx.x * 64 + tid - 32] = 0u; // 1024*64 = 65536

    for (int t = tid; t < 1024; t += 256)
        ((float4*)Ws)[t] = ((const float4*)Wup)[t];
    {
        float4 v = ((const float4*)(fea + r0 * 64))[tid];
        int r = tid >> 4, c = (tid & 15) * 4;
        fs[r*68 + c + 0] = v.x; fs[r*68 + c + 1] = v.y;
        fs[r*68 + c + 2] = v.z; fs[r*68 + c + 3] = v.w;
    }
    __syncthreads();

    const int cg = tid & 15;
    const int r  = tid >> 4;
    float a0 = 0.f, a1 = 0.f, a2 = 0.f, a3 = 0.f;
    const float* fr = fs + r * 68;
    #pragma unroll
    for (int k = 0; k < 64; ++k) {
        float f = fr[k];
        float4 w = *(const float4*)&Ws[k * 64 + cg * 4];
        a0 = fmaf(f, w.x, a0); a1 = fmaf(f, w.y, a1);
        a2 = fmaf(f, w.z, a2); a3 = fmaf(f, w.w, a3);
    }
    a0 = fmaxf(a0, 0.f); a1 = fmaxf(a1, 0.f);
    a2 = fmaxf(a2, 0.f); a3 = fmaxf(a3, 0.f);
    const int row = r0 + r;
    *(float4*)&out_fea[row * 64 + cg * 4] = make_float4(a0, a1, a2, a3);

    float4 wc = *(const float4*)&Wcls[cg * 4];
    float s = a0*wc.x + a1*wc.y + a2*wc.z + a3*wc.w;
    for (int off = 1; off < 16; off <<= 1) s += __shfl_xor(s, off, 16);
    if (cg == 0) out_pred[row] = s;
}

// K2 (round-20 proven shape, 16x1024): bitmask build + per-block byte-0
// partial histogram (phist plain stores) + global hist16 atomicAdd (top 16 bits).
__global__ __launch_bounds__(1024) void k_scat(const float* __restrict__ pred,
        const int* __restrict__ tc, unsigned int* __restrict__ bmask,
        unsigned int* __restrict__ phist, unsigned int* __restrict__ hist16) {
    __shared__ unsigned int whist[16][256];
    const int tid = threadIdx.x;
    const int blk = blockIdx.x;
    const int id = blk * 1024 + tid;

    for (int t = tid; t < 16 * 256; t += 1024) ((unsigned int*)whist)[t] = 0u;

    int4 c = *(const int4*)&tc[id * 4];
    int key = ((c.x * 64 + c.y) * 64 + c.z) * 64 + c.w;
    atomicOr(&bmask[key >> 5], 1u << (key & 31));

    __syncthreads();
    unsigned int u = mono_key(pred[id]);
    atomicAdd(&whist[tid >> 6][u >> 24], 1u);
    atomicAdd(&hist16[u >> 16], 1u);
    __syncthreads();
    if (tid < 256) {
        unsigned int s = 0u;
        #pragma unroll
        for (int w = 0; w < 16; ++w) s += whist[w][tid];
        phist[blk * 256 + tid] = s;
    }
}

// K3: per-block threshold: byte0 from phist sum; byte1 from a 1 KB hist16
// slice; bytes 2-3 from ONE pred scan into an LDS list + tiny radixes
// (exact filtered-scan fallback on overflow). Parallel probe (16 thr/row x 2
// offsets, shfl-min) + epilogue. 64 rows/block.
__global__ __launch_bounds__(1024) void k_final(const int* __restrict__ coords,
        const unsigned int* __restrict__ bmask, const unsigned int* __restrict__ phist,
        const unsigned int* __restrict__ hist16,
        const float* __restrict__ out_pred, float* __restrict__ out_fea,
        float* __restrict__ out_keep, float* __restrict__ out_kt,
        float* __restrict__ out_loss) {
    __shared__ unsigned int hA[256];
    __shared__ unsigned int list[1024];
    __shared__ unsigned int sh_b, sh_r, sh_cnt;
    __shared__ float kscale[64];
    const int tid = threadIdx.x;
    const int r0 = blockIdx.x * 64;

    // ---- byte 0: sum phist partials ----
    if (tid < 256) {
        unsigned int s = 0u;
        #pragma unroll
        for (int b = 0; b < SCAT_NB; ++b) s += phist[b * 256 + tid];
        hA[tid] = s;
    }
    if (tid == 0) sh_cnt = 0u;
    __syncthreads();
    scan_locate256(hA, TPN - 1, &sh_b, &sh_r, tid);
    __syncthreads();
    const unsigned int b0 = sh_b;
    const unsigned int rank1 = sh_r;

    // ---- byte 1: 1 KB slice of hist16 ----
    if (tid < 256) hA[tid] = hist16[b0 * 256 + tid];
    __syncthreads();
    scan_locate256(hA, rank1, &sh_b, &sh_r, tid);
    __syncthreads();
    const unsigned int bin16 = (b0 << 8) | sh_b;
    const unsigned int rank2 = sh_r;

    // ---- collect keys matching bin16 (low 16 bits) in ONE pred scan ----
    for (int i = tid; i < N_PTS / 4; i += 1024) {
        float4 v = ((const float4*)out_pred)[i];
        unsigned int u0 = mono_key(v.x), u1 = mono_key(v.y);
        unsigned int u2 = mono_key(v.z), u3 = mono_key(v.w);
        if ((u0 >> 16) == bin16) { unsigned int p = atomicAdd(&sh_cnt, 1u); if (p < 1024u) list[p] = u0 & 0xFFFFu; }
        if ((u1 >> 16) == bin16) { unsigned int p = atomicAdd(&sh_cnt, 1u); if (p < 1024u) list[p] = u1 & 0xFFFFu; }
        if ((u2 >> 16) == bin16) { unsigned int p = atomicAdd(&sh_cnt, 1u); if (p < 1024u) list[p] = u2 & 0xFFFFu; }
        if ((u3 >> 16) == bin16) { unsigned int p = atomicAdd(&sh_cnt, 1u); if (p < 1024u) list[p] = u3 & 0xFFFFu; }
    }
    __syncthreads();
    const unsigned int cnt = sh_cnt;
    unsigned int b2, b3;

    if (cnt <= 1024u) {                       // list path (order-independent rank)
        if (tid < 256) hA[tid] = 0u;
        __syncthreads();
        if (tid < (int)cnt) atomicAdd(&hA[list[tid] >> 8], 1u);
        __syncthreads();
        scan_locate256(hA, rank2, &sh_b, &sh_r, tid);
        __syncthreads();
        b2 = sh_b;
        unsigned int rank3 = sh_r;
        if (tid < 256) hA[tid] = 0u;
        __syncthreads();
        if (tid < (int)cnt) { unsigned int e = list[tid]; if ((e >> 8) == b2) atomicAdd(&hA[e & 255u], 1u); }
        __syncthreads();
        scan_locate256(hA, rank3, &sh_b, &sh_r, tid);
        __syncthreads();
        b3 = sh_b;
    } else {                                  // exact fallback: filtered pred scans
        if (tid < 256) hA[tid] = 0u;
        __syncthreads();
        for (int i = tid; i < N_PTS / 4; i += 1024) {
            float4 v = ((const float4*)out_pred)[i];
            unsigned int u0 = mono_key(v.x), u1 = mono_key(v.y);
            unsigned int u2 = mono_key(v.z), u3 = mono_key(v.w);
            if ((u0 >> 16) == bin16) atomicAdd(&hA[(u0 >> 8) & 255u], 1u);
            if ((u1 >> 16) == bin16) atomicAdd(&hA[(u1 >> 8) & 255u], 1u);
            if ((u2 >> 16) == bin16) atomicAdd(&hA[(u2 >> 8) & 255u], 1u);
            if ((u3 >> 16) == bin16) atomicAdd(&hA[(u3 >> 8) & 255u], 1u);
        }
        __syncthreads();
        scan_locate256(hA, rank2, &sh_b, &sh_r, tid);
        __syncthreads();
        b2 = sh_b;
        unsigned int rank3 = sh_r;
        unsigned int pfx24 = (bin16 << 8) | b2;
        if (tid < 256) hA[tid] = 0u;
        __syncthreads();
        for (int i = tid; i < N_PTS / 4; i += 1024) {
            float4 v = ((const float4*)out_pred)[i];
            unsigned int u0 = mono_key(v.x), u1 = mono_key(v.y);
            unsigned int u2 = mono_key(v.z), u3 = mono_key(v.w);
            if ((u0 >> 8) == pfx24) atomicAdd(&hA[u0 & 255u], 1u);
            if ((u1 >> 8) == pfx24) atomicAdd(&hA[u1 & 255u], 1u);
            if ((u2 >> 8) == pfx24) atomicAdd(&hA[u2 & 255u], 1u);
            if ((u3 >> 8) == pfx24) atomicAdd(&hA[u3 & 255u], 1u);
        }
        __syncthreads();
        scan_locate256(hA, rank3, &sh_b, &sh_r, tid);
        __syncthreads();
        b3 = sh_b;
    }
    const unsigned int uth = (bin16 << 16) | (b2 << 8) | b3;
    const float thres = (uth & 0x80000000u) ? __uint_as_float(uth ^ 0x80000000u)
                                            : __uint_as_float(~uth);

    // ---- parallel probe: 16 threads/row, 2 offsets each + shfl-min ----
    {
        const int row = tid >> 4;
        const int sub = tid & 15;
        const int i = r0 + row;
        float p = out_pred[i];
        int4 c = *(const int4*)&coords[i * 4];
        const int b = c.x, x = c.y, y = c.z, z = c.w;
        int key0 = ((b * 64 + x) * 64 + y) * 64 + z;
        bool kt = (bmask[key0 >> 5] >> (key0 & 31)) & 1u;
        float dists;
        if (kt) {
            dists = 0.f;
        } else {
            float best = 5.f;                 // sentinel > DUB2: "not found"
            #pragma unroll
            for (int q = 0; q < 2; ++q) {
                int t = 1 + sub + q * 16;     // t in [1,33)
                int ox = x + NOFF4[t][0], oy = y + NOFF4[t][1], oz = z + NOFF4[t][2];
                if (((unsigned)ox | (unsigned)oy | (unsigned)oz) < 64u) {
                    int key = ((b * 64 + ox) * 64 + oy) * 64 + oz;
                    if ((bmask[key >> 5] >> (key & 31)) & 1u)
                        best = fminf(best, (float)NOFF4[t][3]);
                }
            }
            for (int d = 1; d < 16; d <<= 1)
                best = fminf(best, __shfl_xor(best, d, 16));
            dists = best;
        }
        if (sub == 0) {
            bool keep0 = (p <= thres);
            bool pm = (p > DUB2), tm = (dists > DUB2);
            float loss = (pm && tm) ? p : ((!pm && tm) ? DUB2 : dists);
            bool kf = keep0 || kt;
            out_keep[i] = kf ? 1.f : 0.f;
            out_kt[i]  = kt ? 1.f : 0.f;
            out_loss[i] = loss;
            kscale[row] = kf ? 1.f : 0.f;
        }
    }
    __syncthreads();
    {
        float4* fbase = (float4*)(out_fea + r0 * 64);
        int v = tid;                          // 64 rows x 16 float4 = 1024
        float sc = kscale[v >> 4];
        float4 xv = fbase[v];
        xv.x *= sc; xv.y *= sc; xv.z *= sc; xv.w *= sc;
        fbase[v] = xv;
    }
}

extern "C" void kernel_launch(void* const* d_in, const int* in_sizes, int n_in,
                              void* d_out, int out_size, void* d_ws, size_t ws_size,
                              hipStream_t stream) {
    const float* fea     = (const float*)d_in[0];
    const float* Wup     = (const float*)d_in[1];
    const float* Wcls    = (const float*)d_in[2];
    const int*   coords  = (const int*)d_in[3];
    const int*   tcoords = (const int*)d_in[4];

    float* out      = (float*)d_out;
    float* out_pred = out;
    float* out_fea  = out + N_PTS;
    float* out_keep = out + N_PTS + N_PTS * 64;
    float* out_kt   = out_keep + N_PTS;
    float* out_loss = out_kt + N_PTS;

    char* ws = (char*)d_ws;
    unsigned int* bmask  = (unsigned int*)(ws + 64);       // 128 KB -> 131136
    unsigned int* hist16 = (unsigned int*)(ws + 131136);   // 256 KB -> 393280
    unsigned int* phist  = (unsigned int*)(ws + 393280);   // 16 KB  (16 x 256 u32)

    k_gemm <<<N_PTS / 16, 256, 0, stream>>>(fea, Wup, Wcls, out_pred, out_fea,
                                            bmask, hist16);
    k_scat <<<SCAT_NB, 1024, 0, stream>>>(out_pred, tcoords, bmask, phist, hist16);
    k_final<<<N_PTS / 64, 1024, 0, stream>>>(coords, bmask, phist, hist16,
                                             out_pred, out_fea, out_keep, out_kt, out_loss);
}

// Round 30
// 27.004 us; speedup vs baseline: 1.6303x; 1.0615x over previous
//
#include <hip/hip_runtime.h>
#include <math.h>

#define N_PTS 16384
#define M_TGT 16384
#define TPN 8192
#define DUB2 4.0f
#define BMASK_WORDS (4*64*64*64/32)
#define SCAT_NB 16

__device__ __forceinline__ unsigned int mono_key(float f) {
    unsigned int u = __float_as_uint(f);
    return (u & 0x80000000u) ? ~u : (u | 0x80000000u);
}

// 33 integer offsets with dx^2+dy^2+dz^2 <= 4; 4th component = d2 group.
__device__ const signed char NOFF4[33][4] = {
    {0,0,0,0},
    {1,0,0,1},{-1,0,0,1},{0,1,0,1},{0,-1,0,1},{0,0,1,1},{0,0,-1,1},
    {1,1,0,2},{1,-1,0,2},{-1,1,0,2},{-1,-1,0,2},{1,0,1,2},{1,0,-1,2},{-1,0,1,2},{-1,0,-1,2},
    {0,1,1,2},{0,1,-1,2},{0,-1,1,2},{0,-1,-1,2},
    {1,1,1,3},{1,1,-1,3},{1,-1,1,3},{1,-1,-1,3},{-1,1,1,3},{-1,1,-1,3},{-1,-1,1,3},{-1,-1,-1,3},
    {2,0,0,4},{-2,0,0,4},{0,2,0,4},{0,-2,0,4},{0,0,2,4},{0,0,-2,4}
};

// wave-0 scan-locate over a 256-bin LDS histogram: find bin containing rank r,
// write bin -> *sh_b, remaining rank -> *sh_r. Caller barriers around it.
__device__ __forceinline__ void scan_locate256(const unsigned int* h256,
        unsigned int r, unsigned int* sh_b, unsigned int* sh_r, int tid) {
    const int lane = tid & 63;
    if ((tid >> 6) == 0) {
        uint4 h = ((const uint4*)h256)[lane];
        unsigned int ss = h.x + h.y + h.z + h.w;
        unsigned int inc = ss;
        for (int d = 1; d < 64; d <<= 1) {
            unsigned int t = __shfl_up(inc, d);
            if (lane >= d) inc += t;
        }
        unsigned int exc = inc - ss;
        bool has = (r >= exc && r < exc + ss);
        unsigned long long m = __ballot(has);
        if (m != 0ull && lane == __ffsll(m) - 1) {
            unsigned int rr = r - exc;
            if (rr < h.x)                   { *sh_b = lane*4u;    *sh_r = rr; }
            else if (rr < h.x+h.y)          { *sh_b = lane*4u+1u; *sh_r = rr-h.x; }
            else if (rr < h.x+h.y+h.z)      { *sh_b = lane*4u+2u; *sh_r = rr-h.x-h.y; }
            else                            { *sh_b = lane*4u+3u; *sh_r = rr-h.x-h.y-h.z; }
        }
    }
}

// K1: round-11 proven gemm (16 rows/block). Zeroes bmask + hist16.
__global__ __launch_bounds__(256) void k_gemm(const float* __restrict__ fea,
        const float* __restrict__ Wup, const float* __restrict__ Wcls,
        float* __restrict__ out_pred, float* __restrict__ out_fea,
        unsigned int* __restrict__ bmask, unsigned int* __restrict__ hist16) {
    __shared__ float Ws[64 * 64];
    __shared__ float fs[16 * 68];
    const int tid = threadIdx.x;
    const int r0 = blockIdx.x * 16;

    if (tid < 32) bmask[blockIdx.x * 32 + tid] = 0u;            // 1024*32 = 32768
    else if (tid < 96) hist16[blockIdx.x * 64 + tid - 32] = 0u; // 1024*64 = 65536

    for (int t = tid; t < 1024; t += 256)
        ((float4*)Ws)[t] = ((const float4*)Wup)[t];
    {
        float4 v = ((const float4*)(fea + r0 * 64))[tid];
        int r = tid >> 4, c = (tid & 15) * 4;
        fs[r*68 + c + 0] = v.x; fs[r*68 + c + 1] = v.y;
        fs[r*68 + c + 2] = v.z; fs[r*68 + c + 3] = v.w;
    }
    __syncthreads();

    const int cg = tid & 15;
    const int r  = tid >> 4;
    float a0 = 0.f, a1 = 0.f, a2 = 0.f, a3 = 0.f;
    const float* fr = fs + r * 68;
    #pragma unroll
    for (int k = 0; k < 64; ++k) {
        float f = fr[k];
        float4 w = *(const float4*)&Ws[k * 64 + cg * 4];
        a0 = fmaf(f, w.x, a0); a1 = fmaf(f, w.y, a1);
        a2 = fmaf(f, w.z, a2); a3 = fmaf(f, w.w, a3);
    }
    a0 = fmaxf(a0, 0.f); a1 = fmaxf(a1, 0.f);
    a2 = fmaxf(a2, 0.f); a3 = fmaxf(a3, 0.f);
    const int row = r0 + r;
    *(float4*)&out_fea[row * 64 + cg * 4] = make_float4(a0, a1, a2, a3);

    float4 wc = *(const float4*)&Wcls[cg * 4];
    float s = a0*wc.x + a1*wc.y + a2*wc.z + a3*wc.w;
    for (int off = 1; off < 16; off <<= 1) s += __shfl_xor(s, off, 16);
    if (cg == 0) out_pred[row] = s;
}

// K2 (round-20 proven shape, 16x1024): bitmask build + per-block byte-0
// partial histogram (phist plain stores) + global hist16 atomicAdd (top 16 bits).
__global__ __launch_bounds__(1024) void k_scat(const float* __restrict__ pred,
        const int* __restrict__ tc, unsigned int* __restrict__ bmask,
        unsigned int* __restrict__ phist, unsigned int* __restrict__ hist16) {
    __shared__ unsigned int whist[16][256];
    const int tid = threadIdx.x;
    const int blk = blockIdx.x;
    const int id = blk * 1024 + tid;

    for (int t = tid; t < 16 * 256; t += 1024) ((unsigned int*)whist)[t] = 0u;

    int4 c = *(const int4*)&tc[id * 4];
    int key = ((c.x * 64 + c.y) * 64 + c.z) * 64 + c.w;
    atomicOr(&bmask[key >> 5], 1u << (key & 31));

    __syncthreads();
    unsigned int u = mono_key(pred[id]);
    atomicAdd(&whist[tid >> 6][u >> 24], 1u);
    atomicAdd(&hist16[u >> 16], 1u);
    __syncthreads();
    if (tid < 256) {
        unsigned int s = 0u;
        #pragma unroll
        for (int w = 0; w < 16; ++w) s += whist[w][tid];
        phist[blk * 256 + tid] = s;
    }
}

// K3: per-block threshold (phist byte0 -> hist16 slice byte1 -> one pred scan
// + list radix, exact fallback) + parallel probe + WRITE-ONLY epilogue:
// gemm already stored fea_up in out_fea, so kept rows are done; only zero
// the non-kept rows (no read, ~2 MB writes vs 8 MB RMW). 64 rows/block.
__global__ __launch_bounds__(1024) void k_final(const int* __restrict__ coords,
        const unsigned int* __restrict__ bmask, const unsigned int* __restrict__ phist,
        const unsigned int* __restrict__ hist16,
        const float* __restrict__ out_pred, float* __restrict__ out_fea,
        float* __restrict__ out_keep, float* __restrict__ out_kt,
        float* __restrict__ out_loss) {
    __shared__ unsigned int hA[256];
    __shared__ unsigned int list[1024];
    __shared__ unsigned int sh_b, sh_r, sh_cnt;
    __shared__ float kscale[64];
    const int tid = threadIdx.x;
    const int r0 = blockIdx.x * 64;

    // ---- byte 0: sum phist partials ----
    if (tid < 256) {
        unsigned int s = 0u;
        #pragma unroll
        for (int b = 0; b < SCAT_NB; ++b) s += phist[b * 256 + tid];
        hA[tid] = s;
    }
    if (tid == 0) sh_cnt = 0u;
    __syncthreads();
    scan_locate256(hA, TPN - 1, &sh_b, &sh_r, tid);
    __syncthreads();
    const unsigned int b0 = sh_b;
    const unsigned int rank1 = sh_r;

    // ---- byte 1: 1 KB slice of hist16 ----
    if (tid < 256) hA[tid] = hist16[b0 * 256 + tid];
    __syncthreads();
    scan_locate256(hA, rank1, &sh_b, &sh_r, tid);
    __syncthreads();
    const unsigned int bin16 = (b0 << 8) | sh_b;
    const unsigned int rank2 = sh_r;

    // ---- collect keys matching bin16 (low 16 bits) in ONE pred scan ----
    for (int i = tid; i < N_PTS / 4; i += 1024) {
        float4 v = ((const float4*)out_pred)[i];
        unsigned int u0 = mono_key(v.x), u1 = mono_key(v.y);
        unsigned int u2 = mono_key(v.z), u3 = mono_key(v.w);
        if ((u0 >> 16) == bin16) { unsigned int p = atomicAdd(&sh_cnt, 1u); if (p < 1024u) list[p] = u0 & 0xFFFFu; }
        if ((u1 >> 16) == bin16) { unsigned int p = atomicAdd(&sh_cnt, 1u); if (p < 1024u) list[p] = u1 & 0xFFFFu; }
        if ((u2 >> 16) == bin16) { unsigned int p = atomicAdd(&sh_cnt, 1u); if (p < 1024u) list[p] = u2 & 0xFFFFu; }
        if ((u3 >> 16) == bin16) { unsigned int p = atomicAdd(&sh_cnt, 1u); if (p < 1024u) list[p] = u3 & 0xFFFFu; }
    }
    __syncthreads();
    const unsigned int cnt = sh_cnt;
    unsigned int b2, b3;

    if (cnt <= 1024u) {                       // list path (order-independent rank)
        if (tid < 256) hA[tid] = 0u;
        __syncthreads();
        if (tid < (int)cnt) atomicAdd(&hA[list[tid] >> 8], 1u);
        __syncthreads();
        scan_locate256(hA, rank2, &sh_b, &sh_r, tid);
        __syncthreads();
        b2 = sh_b;
        unsigned int rank3 = sh_r;
        if (tid < 256) hA[tid] = 0u;
        __syncthreads();
        if (tid < (int)cnt) { unsigned int e = list[tid]; if ((e >> 8) == b2) atomicAdd(&hA[e & 255u], 1u); }
        __syncthreads();
        scan_locate256(hA, rank3, &sh_b, &sh_r, tid);
        __syncthreads();
        b3 = sh_b;
    } else {                                  // exact fallback: filtered pred scans
        if (tid < 256) hA[tid] = 0u;
        __syncthreads();
        for (int i = tid; i < N_PTS / 4; i += 1024) {
            float4 v = ((const float4*)out_pred)[i];
            unsigned int u0 = mono_key(v.x), u1 = mono_key(v.y);
            unsigned int u2 = mono_key(v.z), u3 = mono_key(v.w);
            if ((u0 >> 16) == bin16) atomicAdd(&hA[(u0 >> 8) & 255u], 1u);
            if ((u1 >> 16) == bin16) atomicAdd(&hA[(u1 >> 8) & 255u], 1u);
            if ((u2 >> 16) == bin16) atomicAdd(&hA[(u2 >> 8) & 255u], 1u);
            if ((u3 >> 16) == bin16) atomicAdd(&hA[(u3 >> 8) & 255u], 1u);
        }
        __syncthreads();
        scan_locate256(hA, rank2, &sh_b, &sh_r, tid);
        __syncthreads();
        b2 = sh_b;
        unsigned int rank3 = sh_r;
        unsigned int pfx24 = (bin16 << 8) | b2;
        if (tid < 256) hA[tid] = 0u;
        __syncthreads();
        for (int i = tid; i < N_PTS / 4; i += 1024) {
            float4 v = ((const float4*)out_pred)[i];
            unsigned int u0 = mono_key(v.x), u1 = mono_key(v.y);
            unsigned int u2 = mono_key(v.z), u3 = mono_key(v.w);
            if ((u0 >> 8) == pfx24) atomicAdd(&hA[u0 & 255u], 1u);
            if ((u1 >> 8) == pfx24) atomicAdd(&hA[u1 & 255u], 1u);
            if ((u2 >> 8) == pfx24) atomicAdd(&hA[u2 & 255u], 1u);
            if ((u3 >> 8) == pfx24) atomicAdd(&hA[u3 & 255u], 1u);
        }
        __syncthreads();
        scan_locate256(hA, rank3, &sh_b, &sh_r, tid);
        __syncthreads();
        b3 = sh_b;
    }
    const unsigned int uth = (bin16 << 16) | (b2 << 8) | b3;
    const float thres = (uth & 0x80000000u) ? __uint_as_float(uth ^ 0x80000000u)
                                            : __uint_as_float(~uth);

    // ---- parallel probe: 16 threads/row, 2 offsets each + shfl-min ----
    {
        const int row = tid >> 4;
        const int sub = tid & 15;
        const int i = r0 + row;
        float p = out_pred[i];
        int4 c = *(const int4*)&coords[i * 4];
        const int b = c.x, x = c.y, y = c.z, z = c.w;
        int key0 = ((b * 64 + x) * 64 + y) * 64 + z;
        bool kt = (bmask[key0 >> 5] >> (key0 & 31)) & 1u;
        float dists;
        if (kt) {
            dists = 0.f;
        } else {
            float best = 5.f;                 // sentinel > DUB2: "not found"
            #pragma unroll
            for (int q = 0; q < 2; ++q) {
                int t = 1 + sub + q * 16;     // t in [1,33)
                int ox = x + NOFF4[t][0], oy = y + NOFF4[t][1], oz = z + NOFF4[t][2];
                if (((unsigned)ox | (unsigned)oy | (unsigned)oz) < 64u) {
                    int key = ((b * 64 + ox) * 64 + oy) * 64 + oz;
                    if ((bmask[key >> 5] >> (key & 31)) & 1u)
                        best = fminf(best, (float)NOFF4[t][3]);
                }
            }
            for (int d = 1; d < 16; d <<= 1)
                best = fminf(best, __shfl_xor(best, d, 16));
            dists = best;
        }
        if (sub == 0) {
            bool keep0 = (p <= thres);
            bool pm = (p > DUB2), tm = (dists > DUB2);
            float loss = (pm && tm) ? p : ((!pm && tm) ? DUB2 : dists);
            bool kf = keep0 || kt;
            out_keep[i] = kf ? 1.f : 0.f;
            out_kt[i]  = kt ? 1.f : 0.f;
            out_loss[i] = loss;
            kscale[row] = kf ? 1.f : 0.f;
        }
    }
    __syncthreads();
    {   // write-only epilogue: zero non-kept rows (kept rows already hold fea_up)
        float4* fbase = (float4*)(out_fea + r0 * 64);
        int v = tid;                          // 64 rows x 16 float4 = 1024
        if (kscale[v >> 4] == 0.f)
            fbase[v] = make_float4(0.f, 0.f, 0.f, 0.f);
    }
}

extern "C" void kernel_launch(void* const* d_in, const int* in_sizes, int n_in,
                              void* d_out, int out_size, void* d_ws, size_t ws_size,
                              hipStream_t stream) {
    const float* fea     = (const float*)d_in[0];
    const float* Wup     = (const float*)d_in[1];
    const float* Wcls    = (const float*)d_in[2];
    const int*   coords  = (const int*)d_in[3];
    const int*   tcoords = (const int*)d_in[4];

    float* out      = (float*)d_out;
    float* out_pred = out;
    float* out_fea  = out + N_PTS;
    float* out_keep = out + N_PTS + N_PTS * 64;
    float* out_kt   = out_keep + N_PTS;
    float* out_loss = out_kt + N_PTS;

    char* ws = (char*)d_ws;
    unsigned int* bmask  = (unsigned int*)(ws + 64);       // 128 KB -> 131136
    unsigned int* hist16 = (unsigned int*)(ws + 131136);   // 256 KB -> 393280
    unsigned int* phist  = (unsigned int*)(ws + 393280);   // 16 KB  (16 x 256 u32)

    k_gemm <<<N_PTS / 16, 256, 0, stream>>>(fea, Wup, Wcls, out_pred, out_fea,
                                            bmask, hist16);
    k_scat <<<SCAT_NB, 1024, 0, stream>>>(out_pred, tcoords, bmask, phist, hist16);
    k_final<<<N_PTS / 64, 1024, 0, stream>>>(coords, bmask, phist, hist16,
                                             out_pred, out_fea, out_keep, out_kt, out_loss);
}

// Round 31
// 25.562 us; speedup vs baseline: 1.7222x; 1.0564x over previous
//
#include <hip/hip_runtime.h>
#include <math.h>

#define N_PTS 16384
#define M_TGT 16384
#define TPN 8192
#define DUB2 4.0f
#define BMASK_WORDS (4*64*64*64/32)
#define SCAT_NB 16

__device__ __forceinline__ unsigned int mono_key(float f) {
    unsigned int u = __float_as_uint(f);
    return (u & 0x80000000u) ? ~u : (u | 0x80000000u);
}

// 33 integer offsets with dx^2+dy^2+dz^2 <= 4; 4th component = d2 group.
__device__ const signed char NOFF4[33][4] = {
    {0,0,0,0},
    {1,0,0,1},{-1,0,0,1},{0,1,0,1},{0,-1,0,1},{0,0,1,1},{0,0,-1,1},
    {1,1,0,2},{1,-1,0,2},{-1,1,0,2},{-1,-1,0,2},{1,0,1,2},{1,0,-1,2},{-1,0,1,2},{-1,0,-1,2},
    {0,1,1,2},{0,1,-1,2},{0,-1,1,2},{0,-1,-1,2},
    {1,1,1,3},{1,1,-1,3},{1,-1,1,3},{1,-1,-1,3},{-1,1,1,3},{-1,1,-1,3},{-1,-1,1,3},{-1,-1,-1,3},
    {2,0,0,4},{-2,0,0,4},{0,2,0,4},{0,-2,0,4},{0,0,2,4},{0,0,-2,4}
};

// wave-0 scan-locate over a 256-bin LDS histogram: find bin containing rank r,
// write bin -> *sh_b, remaining rank -> *sh_r. Caller barriers around it.
__device__ __forceinline__ void scan_locate256(const unsigned int* h256,
        unsigned int r, unsigned int* sh_b, unsigned int* sh_r, int tid) {
    const int lane = tid & 63;
    if ((tid >> 6) == 0) {
        uint4 h = ((const uint4*)h256)[lane];
        unsigned int ss = h.x + h.y + h.z + h.w;
        unsigned int inc = ss;
        for (int d = 1; d < 64; d <<= 1) {
            unsigned int t = __shfl_up(inc, d);
            if (lane >= d) inc += t;
        }
        unsigned int exc = inc - ss;
        bool has = (r >= exc && r < exc + ss);
        unsigned long long m = __ballot(has);
        if (m != 0ull && lane == __ffsll(m) - 1) {
            unsigned int rr = r - exc;
            if (rr < h.x)                   { *sh_b = lane*4u;    *sh_r = rr; }
            else if (rr < h.x+h.y)          { *sh_b = lane*4u+1u; *sh_r = rr-h.x; }
            else if (rr < h.x+h.y+h.z)      { *sh_b = lane*4u+2u; *sh_r = rr-h.x-h.y; }
            else                            { *sh_b = lane*4u+3u; *sh_r = rr-h.x-h.y-h.z; }
        }
    }
}

// K1: round-11 proven gemm (16 rows/block). Zeroes bmask + hist16 + phist.
__global__ __launch_bounds__(256) void k_gemm(const float* __restrict__ fea,
        const float* __restrict__ Wup, const float* __restrict__ Wcls,
        float* __restrict__ out_pred, float* __restrict__ out_fea,
        unsigned int* __restrict__ bmask, unsigned int* __restrict__ hist16,
        unsigned int* __restrict__ phist) {
    __shared__ float Ws[64 * 64];
    __shared__ float fs[16 * 68];
    const int tid = threadIdx.x;
    const int r0 = blockIdx.x * 16;

    if (tid < 32) bmask[blockIdx.x * 32 + tid] = 0u;            // 1024*32 = 32768
    else if (tid < 96) hist16[blockIdx.x * 64 + tid - 32] = 0u; // 1024*64 = 65536
    else if (tid < 100) phist[blockIdx.x * 4 + tid - 96] = 0u;  // 1024*4  = 4096

    for (int t = tid; t < 1024; t += 256)
        ((float4*)Ws)[t] = ((const float4*)Wup)[t];
    {
        float4 v = ((const float4*)(fea + r0 * 64))[tid];
        int r = tid >> 4, c = (tid & 15) * 4;
        fs[r*68 + c + 0] = v.x; fs[r*68 + c + 1] = v.y;
        fs[r*68 + c + 2] = v.z; fs[r*68 + c + 3] = v.w;
    }
    __syncthreads();

    const int cg = tid & 15;
    const int r  = tid >> 4;
    float a0 = 0.f, a1 = 0.f, a2 = 0.f, a3 = 0.f;
    const float* fr = fs + r * 68;
    #pragma unroll
    for (int k = 0; k < 64; ++k) {
        float f = fr[k];
        float4 w = *(const float4*)&Ws[k * 64 + cg * 4];
        a0 = fmaf(f, w.x, a0); a1 = fmaf(f, w.y, a1);
        a2 = fmaf(f, w.z, a2); a3 = fmaf(f, w.w, a3);
    }
    a0 = fmaxf(a0, 0.f); a1 = fmaxf(a1, 0.f);
    a2 = fmaxf(a2, 0.f); a3 = fmaxf(a3, 0.f);
    const int row = r0 + r;
    *(float4*)&out_fea[row * 64 + cg * 4] = make_float4(a0, a1, a2, a3);

    float4 wc = *(const float4*)&Wcls[cg * 4];
    float s = a0*wc.x + a1*wc.y + a2*wc.z + a3*wc.w;
    for (int off = 1; off < 16; off <<= 1) s += __shfl_xor(s, off, 16);
    if (cg == 0) out_pred[row] = s;
}

// K2: 64 blocks x 256 threads (16 blocks was 6% of CUs, latency-bound).
// Bitmask build + per-wave byte-0 hist -> fire-and-forget atomicAdd into
// phist slot blk>>2 (4 blocks/slot; integer accumulation order-independent)
// + global hist16 atomicAdd (top 16 bits).
__global__ __launch_bounds__(256) void k_scat(const float* __restrict__ pred,
        const int* __restrict__ tc, unsigned int* __restrict__ bmask,
        unsigned int* __restrict__ phist, unsigned int* __restrict__ hist16) {
    __shared__ unsigned int whist[4][256];
    const int tid = threadIdx.x;
    const int blk = blockIdx.x;
    const int id = blk * 256 + tid;

    for (int t = tid; t < 4 * 256; t += 256) ((unsigned int*)whist)[t] = 0u;

    int4 c = *(const int4*)&tc[id * 4];
    int key = ((c.x * 64 + c.y) * 64 + c.z) * 64 + c.w;
    atomicOr(&bmask[key >> 5], 1u << (key & 31));

    __syncthreads();
    unsigned int u = mono_key(pred[id]);
    atomicAdd(&whist[tid >> 6][u >> 24], 1u);
    atomicAdd(&hist16[u >> 16], 1u);
    __syncthreads();
    {
        unsigned int s = whist[0][tid] + whist[1][tid] + whist[2][tid] + whist[3][tid];
        if (s) atomicAdd(&phist[(blk >> 2) * 256 + tid], s);
    }
}

// K3: per-block threshold (phist byte0 -> hist16 slice byte1 -> one pred scan
// + list radix, exact fallback) + parallel probe + WRITE-ONLY epilogue.
// 64 rows/block.
__global__ __launch_bounds__(1024) void k_final(const int* __restrict__ coords,
        const unsigned int* __restrict__ bmask, const unsigned int* __restrict__ phist,
        const unsigned int* __restrict__ hist16,
        const float* __restrict__ out_pred, float* __restrict__ out_fea,
        float* __restrict__ out_keep, float* __restrict__ out_kt,
        float* __restrict__ out_loss) {
    __shared__ unsigned int hA[256];
    __shared__ unsigned int list[1024];
    __shared__ unsigned int sh_b, sh_r, sh_cnt;
    __shared__ float kscale[64];
    const int tid = threadIdx.x;
    const int r0 = blockIdx.x * 64;

    // ---- byte 0: sum phist partials ----
    if (tid < 256) {
        unsigned int s = 0u;
        #pragma unroll
        for (int b = 0; b < SCAT_NB; ++b) s += phist[b * 256 + tid];
        hA[tid] = s;
    }
    if (tid == 0) sh_cnt = 0u;
    __syncthreads();
    scan_locate256(hA, TPN - 1, &sh_b, &sh_r, tid);
    __syncthreads();
    const unsigned int b0 = sh_b;
    const unsigned int rank1 = sh_r;

    // ---- byte 1: 1 KB slice of hist16 ----
    if (tid < 256) hA[tid] = hist16[b0 * 256 + tid];
    __syncthreads();
    scan_locate256(hA, rank1, &sh_b, &sh_r, tid);
    __syncthreads();
    const unsigned int bin16 = (b0 << 8) | sh_b;
    const unsigned int rank2 = sh_r;

    // ---- collect keys matching bin16 (low 16 bits) in ONE pred scan ----
    for (int i = tid; i < N_PTS / 4; i += 1024) {
        float4 v = ((const float4*)out_pred)[i];
        unsigned int u0 = mono_key(v.x), u1 = mono_key(v.y);
        unsigned int u2 = mono_key(v.z), u3 = mono_key(v.w);
        if ((u0 >> 16) == bin16) { unsigned int p = atomicAdd(&sh_cnt, 1u); if (p < 1024u) list[p] = u0 & 0xFFFFu; }
        if ((u1 >> 16) == bin16) { unsigned int p = atomicAdd(&sh_cnt, 1u); if (p < 1024u) list[p] = u1 & 0xFFFFu; }
        if ((u2 >> 16) == bin16) { unsigned int p = atomicAdd(&sh_cnt, 1u); if (p < 1024u) list[p] = u2 & 0xFFFFu; }
        if ((u3 >> 16) == bin16) { unsigned int p = atomicAdd(&sh_cnt, 1u); if (p < 1024u) list[p] = u3 & 0xFFFFu; }
    }
    __syncthreads();
    const unsigned int cnt = sh_cnt;
    unsigned int b2, b3;

    if (cnt <= 1024u) {                       // list path (order-independent rank)
        if (tid < 256) hA[tid] = 0u;
        __syncthreads();
        if (tid < (int)cnt) atomicAdd(&hA[list[tid] >> 8], 1u);
        __syncthreads();
        scan_locate256(hA, rank2, &sh_b, &sh_r, tid);
        __syncthreads();
        b2 = sh_b;
        unsigned int rank3 = sh_r;
        if (tid < 256) hA[tid] = 0u;
        __syncthreads();
        if (tid < (int)cnt) { unsigned int e = list[tid]; if ((e >> 8) == b2) atomicAdd(&hA[e & 255u], 1u); }
        __syncthreads();
        scan_locate256(hA, rank3, &sh_b, &sh_r, tid);
        __syncthreads();
        b3 = sh_b;
    } else {                                  // exact fallback: filtered pred scans
        if (tid < 256) hA[tid] = 0u;
        __syncthreads();
        for (int i = tid; i < N_PTS / 4; i += 1024) {
            float4 v = ((const float4*)out_pred)[i];
            unsigned int u0 = mono_key(v.x), u1 = mono_key(v.y);
            unsigned int u2 = mono_key(v.z), u3 = mono_key(v.w);
            if ((u0 >> 16) == bin16) atomicAdd(&hA[(u0 >> 8) & 255u], 1u);
            if ((u1 >> 16) == bin16) atomicAdd(&hA[(u1 >> 8) & 255u], 1u);
            if ((u2 >> 16) == bin16) atomicAdd(&hA[(u2 >> 8) & 255u], 1u);
            if ((u3 >> 16) == bin16) atomicAdd(&hA[(u3 >> 8) & 255u], 1u);
        }
        __syncthreads();
        scan_locate256(hA, rank2, &sh_b, &sh_r, tid);
        __syncthreads();
        b2 = sh_b;
        unsigned int rank3 = sh_r;
        unsigned int pfx24 = (bin16 << 8) | b2;
        if (tid < 256) hA[tid] = 0u;
        __syncthreads();
        for (int i = tid; i < N_PTS / 4; i += 1024) {
            float4 v = ((const float4*)out_pred)[i];
            unsigned int u0 = mono_key(v.x), u1 = mono_key(v.y);
            unsigned int u2 = mono_key(v.z), u3 = mono_key(v.w);
            if ((u0 >> 8) == pfx24) atomicAdd(&hA[u0 & 255u], 1u);
            if ((u1 >> 8) == pfx24) atomicAdd(&hA[u1 & 255u], 1u);
            if ((u2 >> 8) == pfx24) atomicAdd(&hA[u2 & 255u], 1u);
            if ((u3 >> 8) == pfx24) atomicAdd(&hA[u3 & 255u], 1u);
        }
        __syncthreads();
        scan_locate256(hA, rank3, &sh_b, &sh_r, tid);
        __syncthreads();
        b3 = sh_b;
    }
    const unsigned int uth = (bin16 << 16) | (b2 << 8) | b3;
    const float thres = (uth & 0x80000000u) ? __uint_as_float(uth ^ 0x80000000u)
                                            : __uint_as_float(~uth);

    // ---- parallel probe: 16 threads/row, 2 offsets each + shfl-min ----
    {
        const int row = tid >> 4;
        const int sub = tid & 15;
        const int i = r0 + row;
        float p = out_pred[i];
        int4 c = *(const int4*)&coords[i * 4];
        const int b = c.x, x = c.y, y = c.z, z = c.w;
        int key0 = ((b * 64 + x) * 64 + y) * 64 + z;
        bool kt = (bmask[key0 >> 5] >> (key0 & 31)) & 1u;
        float dists;
        if (kt) {
            dists = 0.f;
        } else {
            float best = 5.f;                 // sentinel > DUB2: "not found"
            #pragma unroll
            for (int q = 0; q < 2; ++q) {
                int t = 1 + sub + q * 16;     // t in [1,33)
                int ox = x + NOFF4[t][0], oy = y + NOFF4[t][1], oz = z + NOFF4[t][2];
                if (((unsigned)ox | (unsigned)oy | (unsigned)oz) < 64u) {
                    int key = ((b * 64 + ox) * 64 + oy) * 64 + oz;
                    if ((bmask[key >> 5] >> (key & 31)) & 1u)
                        best = fminf(best, (float)NOFF4[t][3]);
                }
            }
            for (int d = 1; d < 16; d <<= 1)
                best = fminf(best, __shfl_xor(best, d, 16));
            dists = best;
        }
        if (sub == 0) {
            bool keep0 = (p <= thres);
            bool pm = (p > DUB2), tm = (dists > DUB2);
            float loss = (pm && tm) ? p : ((!pm && tm) ? DUB2 : dists);
            bool kf = keep0 || kt;
            out_keep[i] = kf ? 1.f : 0.f;
            out_kt[i]  = kt ? 1.f : 0.f;
            out_loss[i] = loss;
            kscale[row] = kf ? 1.f : 0.f;
        }
    }
    __syncthreads();
    {   // write-only epilogue: zero non-kept rows (kept rows already hold fea_up)
        float4* fbase = (float4*)(out_fea + r0 * 64);
        int v = tid;                          // 64 rows x 16 float4 = 1024
        if (kscale[v >> 4] == 0.f)
            fbase[v] = make_float4(0.f, 0.f, 0.f, 0.f);
    }
}

extern "C" void kernel_launch(void* const* d_in, const int* in_sizes, int n_in,
                              void* d_out, int out_size, void* d_ws, size_t ws_size,
                              hipStream_t stream) {
    const float* fea     = (const float*)d_in[0];
    const float* Wup     = (const float*)d_in[1];
    const float* Wcls    = (const float*)d_in[2];
    const int*   coords  = (const int*)d_in[3];
    const int*   tcoords = (const int*)d_in[4];

    float* out      = (float*)d_out;
    float* out_pred = out;
    float* out_fea  = out + N_PTS;
    float* out_keep = out + N_PTS + N_PTS * 64;
    float* out_kt   = out_keep + N_PTS;
    float* out_loss = out_kt + N_PTS;

    char* ws = (char*)d_ws;
    unsigned int* bmask  = (unsigned int*)(ws + 64);       // 128 KB -> 131136
    unsigned int* hist16 = (unsigned int*)(ws + 131136);   // 256 KB -> 393280
    unsigned int* phist  = (unsigned int*)(ws + 393280);   // 16 KB  (16 x 256 u32)

    k_gemm <<<N_PTS / 16, 256, 0, stream>>>(fea, Wup, Wcls, out_pred, out_fea,
                                            bmask, hist16, phist);
    k_scat <<<64, 256, 0, stream>>>(out_pred, tcoords, bmask, phist, hist16);
    k_final<<<N_PTS / 64, 1024, 0, stream>>>(coords, bmask, phist, hist16,
                                             out_pred, out_fea, out_keep, out_kt, out_loss);
}